// Round 2
// baseline (895.680 us; speedup 1.0000x reference)
//
#include <hip/hip_runtime.h>

#define NU 10000
#define NREV_DST 8000
#define MAIN_GRID 1024

// ws float layout:
//   [0)      Bstate[8*128]   = 1024
//   [1024)   delta_acc[512]
//   [1536)   Wbuf[8*64]      = 512
//   [2048)   allu[NU*16*64]  = 10,240,000   (slots: call1->0..5, call2->6..10, call3->11..15)

__device__ __forceinline__ float rlane(float v, int l) {
    return __int_as_float(__builtin_amdgcn_readlane(__float_as_int(v), l));
}

template <int N, int K>
__global__ __launch_bounds__(256, 4) void main_iter(
    const float* __restrict__ emb, const int* __restrict__ idx,
    const float* __restrict__ Sg, const float* __restrict__ Wg,
    float* __restrict__ delta_acc, float* __restrict__ allu,
    int slot0, int write_high, int write_delta)
{
    constexpr int NC = (N + 31) / 32;
    __shared__ float s_emb[4][32 * 65];   // per-wave chunk buffer, 33,280 B total

    const int tid  = threadIdx.x;
    const int w    = tid >> 6;
    const int lane = tid & 63;
    const int tw   = gridDim.x * 4;
    const int gw   = blockIdx.x * 4 + w;

    float dreg[K];   // lane n owns delta[k][n] fully (accumulated over e and users)
#pragma unroll
    for (int k = 0; k < K; ++k) dreg[k] = 0.f;

    for (int u = gw; u < NU; u += tw) {
        // ---- phase A: g[k][e=lane] = sum_r W[k][r] * emb[r][e]  (LDS transpose, 32-row chunks)
        float g[K];
#pragma unroll
        for (int k = 0; k < K; ++k) g[k] = 0.f;

        for (int c = 0; c < NC; ++c) {
            const int m = (N - c * 32 < 32) ? (N - c * 32) : 32;
            const int npass = (m + 3) >> 2;
            for (int p = 0; p < npass; ++p) {
                const int r = p * 4 + (lane >> 4);
                if (r < m) {
                    const int row = idx[u * N + c * 32 + r];
                    const float4 v = *reinterpret_cast<const float4*>(
                        emb + (size_t)row * 64 + (lane & 15) * 4);
                    float* dst = &s_emb[w][r * 65 + (lane & 15) * 4];
                    dst[0] = v.x; dst[1] = v.y; dst[2] = v.z; dst[3] = v.w;
                }
            }
            for (int r = 0; r < m; r += 2) {   // m always even (32 or 18)
                const float e0 = s_emb[w][r * 65 + lane];
                const float e1 = s_emb[w][(r + 1) * 65 + lane];
#pragma unroll
                for (int k = 0; k < K; ++k) {
                    g[k] = fmaf(Wg[k * 64 + c * 32 + r],     e0, g[k]);
                    g[k] = fmaf(Wg[k * 64 + c * 32 + r + 1], e1, g[k]);
                }
            }
        }

        // ---- phase B: raw[k][d=lane] = sum_e g[k][e] * S[e][d]   (S from global, L1-hot)
        float raw[K];
#pragma unroll
        for (int k = 0; k < K; ++k) raw[k] = 0.f;
        for (int e0 = 0; e0 < 64; e0 += 4) {
            float sv0 = Sg[(e0 + 0) * 64 + lane];
            float sv1 = Sg[(e0 + 1) * 64 + lane];
            float sv2 = Sg[(e0 + 2) * 64 + lane];
            float sv3 = Sg[(e0 + 3) * 64 + lane];
#pragma unroll
            for (int k = 0; k < K; ++k) {
                raw[k] = fmaf(rlane(g[k], e0 + 0), sv0, raw[k]);
                raw[k] = fmaf(rlane(g[k], e0 + 1), sv1, raw[k]);
                raw[k] = fmaf(rlane(g[k], e0 + 2), sv2, raw[k]);
                raw[k] = fmaf(rlane(g[k], e0 + 3), sv3, raw[k]);
            }
        }

        // ---- squash (sum over k, per d)
        float sq = 0.f;
#pragma unroll
        for (int k = 0; k < K; ++k) sq = fmaf(raw[k], raw[k], sq);
        const float f = (sq / (1.0f + sq)) / sqrtf(sq + 1e-9f);
        float hi[K];
#pragma unroll
        for (int k = 0; k < K; ++k) hi[k] = f * raw[k];
        if (write_high) {
#pragma unroll
            for (int k = 0; k < K; ++k)
                allu[(size_t)u * 1024 + (slot0 + k) * 64 + lane] = hi[k];
        }

        if (write_delta) {
            // ---- phase C: hs[k][e=lane] = sum_d hi[k][d] * S[e][d]  (row e of S, float4, L1-hot)
            float hs[K];
#pragma unroll
            for (int k = 0; k < K; ++k) hs[k] = 0.f;
            for (int d0 = 0; d0 < 64; d0 += 4) {
                const float4 sr = *reinterpret_cast<const float4*>(Sg + lane * 64 + d0);
#pragma unroll
                for (int k = 0; k < K; ++k) {
                    hs[k] = fmaf(rlane(hi[k], d0 + 0), sr.x, hs[k]);
                    hs[k] = fmaf(rlane(hi[k], d0 + 1), sr.y, hs[k]);
                    hs[k] = fmaf(rlane(hi[k], d0 + 2), sr.z, hs[k]);
                    hs[k] = fmaf(rlane(hi[k], d0 + 3), sr.w, hs[k]);
                }
            }
            // ---- phase D: delta[k][n=lane] += sum_e emb[n][e] * hs[k][e]  (emb from global/L2)
            const int nclamp = (lane < N) ? lane : 0;   // lanes >= N accumulate garbage, masked at write
            const int row = idx[u * N + nclamp];
            const float* ep = emb + (size_t)row * 64;
            for (int e0 = 0; e0 < 64; e0 += 4) {
                const float4 ev = *reinterpret_cast<const float4*>(ep + e0);
#pragma unroll
                for (int k = 0; k < K; ++k) {
                    dreg[k] = fmaf(ev.x, rlane(hs[k], e0 + 0), dreg[k]);
                    dreg[k] = fmaf(ev.y, rlane(hs[k], e0 + 1), dreg[k]);
                    dreg[k] = fmaf(ev.z, rlane(hs[k], e0 + 2), dreg[k]);
                    dreg[k] = fmaf(ev.w, rlane(hs[k], e0 + 3), dreg[k]);
                }
            }
        }
    }

    if (write_delta) {
        __syncthreads();   // all waves done with their s_emb regions
        float* sflat = &s_emb[0][0];
#pragma unroll
        for (int k = 0; k < K; ++k) sflat[(w * K + k) * 64 + lane] = dreg[k];
        __syncthreads();
        for (int t = tid; t < K * 64; t += 256) {
            const float s = sflat[t] + sflat[K * 64 + t] + sflat[2 * K * 64 + t] + sflat[3 * K * 64 + t];
            if ((t & 63) < N) atomicAdd(&delta_acc[t], s);
        }
    }
}

// Apply delta -> B, zero delta, compute next softmax W.
__global__ __launch_bounds__(1024) void update_kernel(
    float* __restrict__ Bstate, float* __restrict__ delta_acc,
    const float* __restrict__ Bin, float* __restrict__ Wout,
    int init, int Kc, int nc, int Kn, int nn)
{
    __shared__ float sB[1024];
    const int t = threadIdx.x;
    float b = init ? Bin[t] : Bstate[t];
    const int k = t >> 7, n = t & 127;
    float d = 0.f;
    if (!init && k < Kc && n < nc) d = delta_acc[k * 64 + n];
    __syncthreads();
    if (t < 512) delta_acc[t] = 0.f;  // fresh accumulator for next main launch
    b += d;
    Bstate[t] = b;
    sB[t] = b;
    __syncthreads();
    const int wv = t >> 6, lane = t & 63;
    if (wv < Kn) {
        float v = (lane < nn) ? sB[wv * 128 + lane] : -3.4e38f;
        float m = v;
#pragma unroll
        for (int off = 32; off >= 1; off >>= 1) m = fmaxf(m, __shfl_xor(m, off, 64));
        const float e = (lane < nn) ? expf(v - m) : 0.f;
        float s = e;
#pragma unroll
        for (int off = 32; off >= 1; off >>= 1) s += __shfl_xor(s, off, 64);
        Wout[wv * 64 + lane] = e / s;
    }
}

__global__ __launch_bounds__(256) void attn_kernel(
    const float* __restrict__ allu, const float* __restrict__ M1g,
    const float* __restrict__ M2g, float* __restrict__ out)
{
    __shared__ float sM1[64 * 65];
    __shared__ float sU[4][16 * 64];
    const int tid = threadIdx.x, w = tid >> 6, lane = tid & 63;
    for (int i = tid; i < 4096; i += 256)
        sM1[(i >> 6) * 65 + (i & 63)] = M1g[i];
    __syncthreads();
    const int u = blockIdx.x * 4 + w;
    if (u >= NU) return;
    for (int i = 0; i < 16; ++i)
        sU[w][i * 64 + lane] = allu[(size_t)u * 1024 + i * 64 + lane];
    const float m2 = M2g[lane];
    float acc[16];
#pragma unroll
    for (int i = 0; i < 16; ++i) acc[i] = 0.f;
    for (int d = 0; d < 64; ++d) {
        const float m1v = sM1[d * 65 + lane];
#pragma unroll
        for (int i = 0; i < 16; ++i) acc[i] = fmaf(sU[w][i * 64 + d], m1v, acc[i]);
    }
    float s2[16];
#pragma unroll
    for (int i = 0; i < 16; ++i) {
        float c = tanhf(acc[i]) * m2;
#pragma unroll
        for (int off = 32; off >= 1; off >>= 1) c += __shfl_xor(c, off, 64);
        s2[i] = c * c;
    }
    float mx = 0.f;  // 8 padded slots have s=0
#pragma unroll
    for (int i = 0; i < 16; ++i) mx = fmaxf(mx, s2[i]);
    float den = 8.f * expf(-mx);
    float att[16];
#pragma unroll
    for (int i = 0; i < 16; ++i) { att[i] = expf(s2[i] - mx); den += att[i]; }
    const float inv = 1.0f / den;
    float o = 0.f;
#pragma unroll
    for (int i = 0; i < 16; ++i) o = fmaf(att[i] * inv, sU[w][i * 64 + lane], o);
    out[(size_t)u * 64 + lane] = o;
}

__global__ __launch_bounds__(256) void review_kernel(
    const float* __restrict__ tag, const int* __restrict__ idx, float* __restrict__ out)
{
    const int tid = threadIdx.x, w = tid >> 6, lane = tid & 63;
    const int r = blockIdx.x * 4 + w;
    if (r >= NREV_DST) return;
    float acc = 0.f;
    for (int j = 0; j < 20; ++j) {
        const int t = idx[r * 20 + j];
        acc += tag[(size_t)t * 64 + lane];
    }
    out[(size_t)r * 64 + lane] = acc / 20.0f;
}

extern "C" void kernel_launch(void* const* d_in, const int* in_sizes, int n_in,
                              void* d_out, int out_size, void* d_ws, size_t ws_size,
                              hipStream_t stream)
{
    const float* review_embed = (const float*)d_in[0];
    const float* tag_embed    = (const float*)d_in[1];
    const int*   idx_urt      = (const int*)d_in[2];
    const int*   idx_uqt      = (const int*)d_in[3];
    const int*   idx_uprt     = (const int*)d_in[4];
    const int*   idx_rht      = (const int*)d_in[5];
    const float* B_in         = (const float*)d_in[6];
    const float* S_g          = (const float*)d_in[7];
    const float* M1           = (const float*)d_in[8];
    const float* M2           = (const float*)d_in[9];

    float* ws     = (float*)d_ws;
    float* Bstate = ws;
    float* delta  = ws + 1024;
    float* Wbuf   = ws + 1536;
    float* allu   = ws + 2048;
    float* out    = (float*)d_out;

    const dim3 mg(MAIN_GRID), mb(256);
    const dim3 one(1), ub(1024);

    // init: copy B, zero delta, W for call1 (K=6, n=64)
    hipLaunchKernelGGL(update_kernel, one, ub, 0, stream,
                       Bstate, delta, B_in, Wbuf, 1, 0, 0, 6, 64);

    // call 1: review_embed[idx_urt], n=64, K=6, slots 0..5
    for (int itr = 0; itr < 3; ++itr) {
        hipLaunchKernelGGL((main_iter<64, 6>), mg, mb, 0, stream,
                           review_embed, idx_urt, S_g, Wbuf, delta, allu,
                           0, (itr == 2) ? 1 : 0, 1);
        const int Kn = (itr == 2) ? 5 : 6;
        const int nn = (itr == 2) ? 32 : 64;
        hipLaunchKernelGGL(update_kernel, one, ub, 0, stream,
                           Bstate, delta, B_in, Wbuf, 0, 6, 64, Kn, nn);
    }
    // call 2: tag_embed[idx_uqt], n=32, K=5, slots 6..10
    for (int itr = 0; itr < 3; ++itr) {
        hipLaunchKernelGGL((main_iter<32, 5>), mg, mb, 0, stream,
                           tag_embed, idx_uqt, S_g, Wbuf, delta, allu,
                           6, (itr == 2) ? 1 : 0, 1);
        const int nn = (itr == 2) ? 50 : 32;
        hipLaunchKernelGGL(update_kernel, one, ub, 0, stream,
                           Bstate, delta, B_in, Wbuf, 0, 5, 32, 5, nn);
    }
    // call 3: review_embed[idx_uprt], n=50, K=5, slots 11..15
    for (int itr = 0; itr < 3; ++itr) {
        const int last = (itr == 2);
        hipLaunchKernelGGL((main_iter<50, 5>), mg, mb, 0, stream,
                           review_embed, idx_uprt, S_g, Wbuf, delta, allu,
                           11, last, last ? 0 : 1);
        if (!last)
            hipLaunchKernelGGL(update_kernel, one, ub, 0, stream,
                               Bstate, delta, B_in, Wbuf, 0, 5, 50, 5, 50);
    }

    hipLaunchKernelGGL(attn_kernel, dim3((NU + 3) / 4), mb, 0, stream, allu, M1, M2, out);
    hipLaunchKernelGGL(review_kernel, dim3((NREV_DST + 3) / 4), mb, 0, stream,
                       tag_embed, idx_rht, out + (size_t)NU * 64);
}

// Round 3
// 834.572 us; speedup vs baseline: 1.0732x; 1.0732x over previous
//
#include <hip/hip_runtime.h>

#define NU 10000
#define NREV_DST 8000
#define MAIN_GRID 512   // 2 blocks/CU x 256 CU resident

// ws float layout:
//   [0)      Bstate[8*128]   = 1024
//   [1024)   delta_acc[512]
//   [1536)   Wbuf[8*64]      = 512
//   [2048)   allu[NU*16*64]  = 10,240,000   (slots: call1->0..5, call2->6..10, call3->11..15)

template <int N, int K>
__global__ __launch_bounds__(256, 2) void main_iter(
    const float* __restrict__ emb, const int* __restrict__ idx,
    const float* __restrict__ Sg, const float* __restrict__ Wg,
    float* __restrict__ delta_acc, float* __restrict__ allu,
    int slot0, int write_high, int write_delta)
{
    constexpr int NC = (N + 31) / 32;
    constexpr int KP = K * NC * 32;

    __shared__ float s_S[64 * 65];          // 16.6 KB, block-shared, both orientations conflict-free
    __shared__ float s_emb[4][32 * 65];     // 33.3 KB, per-wave chunk buffer (stride 65)
    __shared__ float s_kb[4][K * 64];       // per-wave g/hi/hs scratch (contiguous -> b128 broadcast)

    const int tid  = threadIdx.x;
    const int w    = tid >> 6;
    const int lane = tid & 63;
    const int tw   = gridDim.x * 4;
    const int gw   = blockIdx.x * 4 + w;

    // stage S (row-major, stride 65): B reads s_S[e*65+lane], C reads s_S[lane*65+d] - both conflict-free
    for (int i = tid; i < 64 * 64; i += 256)
        s_S[(i >> 6) * 65 + (i & 63)] = Sg[i];
    __syncthreads();

    float dreg[NC][K];
#pragma unroll
    for (int c = 0; c < NC; ++c)
#pragma unroll
        for (int k = 0; k < K; ++k) dreg[c][k] = 0.f;

    auto stage = [&](int u, int c, int m) {
        const int npass = (m + 3) >> 2;
        for (int p = 0; p < npass; ++p) {
            const int r = p * 4 + (lane >> 4);
            if (r < m) {
                const int row = idx[u * N + c * 32 + r];
                const float4 v = *reinterpret_cast<const float4*>(
                    emb + (size_t)row * 64 + (lane & 15) * 4);
                float* dst = &s_emb[w][r * 65 + (lane & 15) * 4];
                dst[0] = v.x; dst[1] = v.y; dst[2] = v.z; dst[3] = v.w;
            }
        }
    };

    for (int u = gw; u < NU; u += tw) {
        // ---- phase A: g[k][e=lane] = sum_r W[k][r] * emb[r][e]
        float g[K];
#pragma unroll
        for (int k = 0; k < K; ++k) g[k] = 0.f;
        for (int c = 0; c < NC; ++c) {
            const int m = (N - c * 32 < 32) ? (N - c * 32) : 32;
            stage(u, c, m);
            for (int r = 0; r < m; r += 2) {   // m is always even (32 or 18)
                const float e0 = s_emb[w][r * 65 + lane];
                const float e1 = s_emb[w][(r + 1) * 65 + lane];
#pragma unroll
                for (int k = 0; k < K; ++k) {
                    g[k] = fmaf(Wg[k * 64 + c * 32 + r],     e0, g[k]);  // uniform -> s_load
                    g[k] = fmaf(Wg[k * 64 + c * 32 + r + 1], e1, g[k]);
                }
            }
        }

        // ---- phase B: raw[k][d=lane] = sum_e g[k][e] * S[e][d]
        //      g broadcast via wave-uniform ds_read_b128 (4 e-values per issue)
#pragma unroll
        for (int k = 0; k < K; ++k) s_kb[w][k * 64 + lane] = g[k];
        float raw[K];
#pragma unroll
        for (int k = 0; k < K; ++k) raw[k] = 0.f;
        for (int e0 = 0; e0 < 64; e0 += 4) {
            const float sv0 = s_S[(e0 + 0) * 65 + lane];
            const float sv1 = s_S[(e0 + 1) * 65 + lane];
            const float sv2 = s_S[(e0 + 2) * 65 + lane];
            const float sv3 = s_S[(e0 + 3) * 65 + lane];
#pragma unroll
            for (int k = 0; k < K; ++k) {
                const float4 gb = *reinterpret_cast<const float4*>(&s_kb[w][k * 64 + e0]);
                raw[k] = fmaf(gb.x, sv0, raw[k]);
                raw[k] = fmaf(gb.y, sv1, raw[k]);
                raw[k] = fmaf(gb.z, sv2, raw[k]);
                raw[k] = fmaf(gb.w, sv3, raw[k]);
            }
        }

        // ---- squash (sum over k, per d)
        float sq = 0.f;
#pragma unroll
        for (int k = 0; k < K; ++k) sq = fmaf(raw[k], raw[k], sq);
        const float f = (sq / (1.0f + sq)) / sqrtf(sq + 1e-9f);
        float hi[K];
#pragma unroll
        for (int k = 0; k < K; ++k) hi[k] = f * raw[k];
        if (write_high) {
#pragma unroll
            for (int k = 0; k < K; ++k)
                allu[(size_t)u * 1024 + (slot0 + k) * 64 + lane] = hi[k];
        }

        if (write_delta) {
            // ---- phase C: hs[k][e=lane] = sum_d hi[k][d] * S[e][d]
#pragma unroll
            for (int k = 0; k < K; ++k) s_kb[w][k * 64 + lane] = hi[k];  // reuse (B reads done)
            float hs[K];
#pragma unroll
            for (int k = 0; k < K; ++k) hs[k] = 0.f;
            for (int d0 = 0; d0 < 64; d0 += 4) {
                const float t0 = s_S[lane * 65 + d0 + 0];
                const float t1 = s_S[lane * 65 + d0 + 1];
                const float t2 = s_S[lane * 65 + d0 + 2];
                const float t3 = s_S[lane * 65 + d0 + 3];
#pragma unroll
                for (int k = 0; k < K; ++k) {
                    const float4 hb = *reinterpret_cast<const float4*>(&s_kb[w][k * 64 + d0]);
                    hs[k] = fmaf(hb.x, t0, hs[k]);
                    hs[k] = fmaf(hb.y, t1, hs[k]);
                    hs[k] = fmaf(hb.z, t2, hs[k]);
                    hs[k] = fmaf(hb.w, t3, hs[k]);
                }
            }
#pragma unroll
            for (int k = 0; k < K; ++k) s_kb[w][k * 64 + lane] = hs[k];  // reuse again

            // ---- phase D: delta[k][n] += sum_e emb[n][e] * hs[k][e]
            //      lane = (nl, h): row nl of chunk, e-half h. hs via 2-address b128 bcast (2-way = free)
            const int nl = lane & 31, h = lane >> 5;
#pragma unroll
            for (int cc = NC - 1; cc >= 0; --cc) {
                const int m = (N - cc * 32 < 32) ? (N - cc * 32) : 32;
                if (cc != NC - 1) stage(u, cc, m);   // last chunk still resident from phase A
                if (nl < m) {
                    for (int eh0 = 0; eh0 < 32; eh0 += 4) {
                        const float* ep = &s_emb[w][nl * 65 + h * 32 + eh0];
                        const float e_0 = ep[0], e_1 = ep[1], e_2 = ep[2], e_3 = ep[3];
#pragma unroll
                        for (int k = 0; k < K; ++k) {
                            const float4 hb = *reinterpret_cast<const float4*>(
                                &s_kb[w][k * 64 + h * 32 + eh0]);
                            dreg[cc][k] = fmaf(e_0, hb.x, dreg[cc][k]);
                            dreg[cc][k] = fmaf(e_1, hb.y, dreg[cc][k]);
                            dreg[cc][k] = fmaf(e_2, hb.z, dreg[cc][k]);
                            dreg[cc][k] = fmaf(e_3, hb.w, dreg[cc][k]);
                        }
                    }
                }
            }
        }
    }

    if (write_delta) {
        __syncthreads();   // all waves done with s_emb
        float* sf = &s_emb[0][0];
        const int nl = lane & 31;
#pragma unroll
        for (int cc = 0; cc < NC; ++cc) {
#pragma unroll
            for (int k = 0; k < K; ++k) {
                const float v = dreg[cc][k] + __shfl_xor(dreg[cc][k], 32, 64);
                if (lane < 32) sf[w * KP + (k * NC + cc) * 32 + nl] = v;
            }
        }
        __syncthreads();
        for (int t = tid; t < KP; t += 256) {
            const float s = sf[t] + sf[KP + t] + sf[2 * KP + t] + sf[3 * KP + t];
            const int k = t / (NC * 32), n = t % (NC * 32);
            if (n < N) atomicAdd(&delta_acc[k * 64 + n], s);
        }
    }
}

// Apply delta -> B, zero delta, compute next softmax W.
__global__ __launch_bounds__(1024) void update_kernel(
    float* __restrict__ Bstate, float* __restrict__ delta_acc,
    const float* __restrict__ Bin, float* __restrict__ Wout,
    int init, int Kc, int nc, int Kn, int nn)
{
    __shared__ float sB[1024];
    const int t = threadIdx.x;
    float b = init ? Bin[t] : Bstate[t];
    const int k = t >> 7, n = t & 127;
    float d = 0.f;
    if (!init && k < Kc && n < nc) d = delta_acc[k * 64 + n];
    __syncthreads();
    if (t < 512) delta_acc[t] = 0.f;  // fresh accumulator for next main launch
    b += d;
    Bstate[t] = b;
    sB[t] = b;
    __syncthreads();
    const int wv = t >> 6, lane = t & 63;
    if (wv < Kn) {
        float v = (lane < nn) ? sB[wv * 128 + lane] : -3.4e38f;
        float m = v;
#pragma unroll
        for (int off = 32; off >= 1; off >>= 1) m = fmaxf(m, __shfl_xor(m, off, 64));
        const float e = (lane < nn) ? expf(v - m) : 0.f;
        float s = e;
#pragma unroll
        for (int off = 32; off >= 1; off >>= 1) s += __shfl_xor(s, off, 64);
        Wout[wv * 64 + lane] = e / s;
    }
}

__global__ __launch_bounds__(256) void attn_kernel(
    const float* __restrict__ allu, const float* __restrict__ M1g,
    const float* __restrict__ M2g, float* __restrict__ out)
{
    __shared__ float sM1[64 * 65];
    __shared__ float sU[4][16 * 64];
    const int tid = threadIdx.x, w = tid >> 6, lane = tid & 63;
    for (int i = tid; i < 4096; i += 256)
        sM1[(i >> 6) * 65 + (i & 63)] = M1g[i];
    __syncthreads();
    const int u = blockIdx.x * 4 + w;
    if (u >= NU) return;
    for (int i = 0; i < 16; ++i)
        sU[w][i * 64 + lane] = allu[(size_t)u * 1024 + i * 64 + lane];
    const float m2 = M2g[lane];
    float acc[16];
#pragma unroll
    for (int i = 0; i < 16; ++i) acc[i] = 0.f;
    for (int d = 0; d < 64; ++d) {
        const float m1v = sM1[d * 65 + lane];
#pragma unroll
        for (int i = 0; i < 16; ++i) acc[i] = fmaf(sU[w][i * 64 + d], m1v, acc[i]);
    }
    float s2[16];
#pragma unroll
    for (int i = 0; i < 16; ++i) {
        float c = tanhf(acc[i]) * m2;
#pragma unroll
        for (int off = 32; off >= 1; off >>= 1) c += __shfl_xor(c, off, 64);
        s2[i] = c * c;
    }
    float mx = 0.f;  // 8 padded slots have s=0
#pragma unroll
    for (int i = 0; i < 16; ++i) mx = fmaxf(mx, s2[i]);
    float den = 8.f * expf(-mx);
    float att[16];
#pragma unroll
    for (int i = 0; i < 16; ++i) { att[i] = expf(s2[i] - mx); den += att[i]; }
    const float inv = 1.0f / den;
    float o = 0.f;
#pragma unroll
    for (int i = 0; i < 16; ++i) o = fmaf(att[i] * inv, sU[w][i * 64 + lane], o);
    out[(size_t)u * 64 + lane] = o;
}

__global__ __launch_bounds__(256) void review_kernel(
    const float* __restrict__ tag, const int* __restrict__ idx, float* __restrict__ out)
{
    const int tid = threadIdx.x, w = tid >> 6, lane = tid & 63;
    const int r = blockIdx.x * 4 + w;
    if (r >= NREV_DST) return;
    float acc = 0.f;
    for (int j = 0; j < 20; ++j) {
        const int t = idx[r * 20 + j];
        acc += tag[(size_t)t * 64 + lane];
    }
    out[(size_t)r * 64 + lane] = acc / 20.0f;
}

extern "C" void kernel_launch(void* const* d_in, const int* in_sizes, int n_in,
                              void* d_out, int out_size, void* d_ws, size_t ws_size,
                              hipStream_t stream)
{
    const float* review_embed = (const float*)d_in[0];
    const float* tag_embed    = (const float*)d_in[1];
    const int*   idx_urt      = (const int*)d_in[2];
    const int*   idx_uqt      = (const int*)d_in[3];
    const int*   idx_uprt     = (const int*)d_in[4];
    const int*   idx_rht      = (const int*)d_in[5];
    const float* B_in         = (const float*)d_in[6];
    const float* S_g          = (const float*)d_in[7];
    const float* M1           = (const float*)d_in[8];
    const float* M2           = (const float*)d_in[9];

    float* ws     = (float*)d_ws;
    float* Bstate = ws;
    float* delta  = ws + 1024;
    float* Wbuf   = ws + 1536;
    float* allu   = ws + 2048;
    float* out    = (float*)d_out;

    const dim3 mg(MAIN_GRID), mb(256);
    const dim3 one(1), ub(1024);

    // init: copy B, zero delta, W for call1 (K=6, n=64)
    hipLaunchKernelGGL(update_kernel, one, ub, 0, stream,
                       Bstate, delta, B_in, Wbuf, 1, 0, 0, 6, 64);

    // call 1: review_embed[idx_urt], n=64, K=6, slots 0..5
    for (int itr = 0; itr < 3; ++itr) {
        hipLaunchKernelGGL((main_iter<64, 6>), mg, mb, 0, stream,
                           review_embed, idx_urt, S_g, Wbuf, delta, allu,
                           0, (itr == 2) ? 1 : 0, 1);
        const int Kn = (itr == 2) ? 5 : 6;
        const int nn = (itr == 2) ? 32 : 64;
        hipLaunchKernelGGL(update_kernel, one, ub, 0, stream,
                           Bstate, delta, B_in, Wbuf, 0, 6, 64, Kn, nn);
    }
    // call 2: tag_embed[idx_uqt], n=32, K=5, slots 6..10
    for (int itr = 0; itr < 3; ++itr) {
        hipLaunchKernelGGL((main_iter<32, 5>), mg, mb, 0, stream,
                           tag_embed, idx_uqt, S_g, Wbuf, delta, allu,
                           6, (itr == 2) ? 1 : 0, 1);
        const int nn = (itr == 2) ? 50 : 32;
        hipLaunchKernelGGL(update_kernel, one, ub, 0, stream,
                           Bstate, delta, B_in, Wbuf, 0, 5, 32, 5, nn);
    }
    // call 3: review_embed[idx_uprt], n=50, K=5, slots 11..15
    for (int itr = 0; itr < 3; ++itr) {
        const int last = (itr == 2);
        hipLaunchKernelGGL((main_iter<50, 5>), mg, mb, 0, stream,
                           review_embed, idx_uprt, S_g, Wbuf, delta, allu,
                           11, last, last ? 0 : 1);
        if (!last)
            hipLaunchKernelGGL(update_kernel, one, ub, 0, stream,
                               Bstate, delta, B_in, Wbuf, 0, 5, 50, 5, 50);
    }

    hipLaunchKernelGGL(attn_kernel, dim3((NU + 3) / 4), mb, 0, stream, allu, M1, M2, out);
    hipLaunchKernelGGL(review_kernel, dim3((NREV_DST + 3) / 4), mb, 0, stream,
                       tag_embed, idx_rht, out + (size_t)NU * 64);
}